// Round 11
// baseline (535.368 us; speedup 1.0000x reference)
//
#include <hip/hip_runtime.h>

typedef float v2f __attribute__((ext_vector_type(2)));

// ---------- zero int buffer ----------
__global__ void zero_k(int* __restrict__ p, int n) {
  int i = blockIdx.x * blockDim.x + threadIdx.x;
  if (i < n) p[i] = 0;
}

// ---------- histogram of dst ----------
__global__ void hist_k(const int* __restrict__ ei, int* __restrict__ cnt, int E) {
  int e = blockIdx.x * blockDim.x + threadIdx.x;
  if (e < E) atomicAdd(&cnt[ei[E + e]], 1);
}

// ---------- M precompute: M[k][j][h] = sum_o W2b[j][o]*Wr1[k*16+o][h] ----------
__global__ void mk_k(const float* __restrict__ W2b, const float* __restrict__ Wr1,
                     float* __restrict__ M) {
  int idx = blockIdx.x * 256 + threadIdx.x;   // 32768 total
  int k = idx >> 12, j = (idx >> 6) & 63, h = idx & 63;
  float m = 0.f;
  #pragma unroll
  for (int o = 0; o < 16; ++o) m = fmaf(W2b[j*16 + o], Wr1[(k*16 + o)*64 + h], m);
  M[idx] = m;
}

// ---------- single-block scan + fused weight precompute (SV4, C0) ----------
__global__ void scan_k(int* __restrict__ ptr, int* __restrict__ cur, int N,
                       const float* __restrict__ W0, const float* __restrict__ b0,
                       const float* __restrict__ W1, const float* __restrict__ b1,
                       const float* __restrict__ W2a, const float* __restrict__ b2a,
                       const float* __restrict__ b2b, const float* __restrict__ br1,
                       const float* __restrict__ Wr1,
                       float4* __restrict__ SV4, float* __restrict__ C0) {
  __shared__ int sums[256];
  __shared__ float w01[64], g[64];
  int t = threadIdx.x;
  int chunk = (N + 255) / 256;
  int lo = t * chunk, hi = lo + chunk; if (hi > N) hi = N; if (lo > N) lo = N;
  int s = 0;
  for (int i = lo; i < hi; ++i) s += ptr[i];
  sums[t] = s;
  if (t < 64) {
    float a = 0.f, bg = 0.f;
    for (int i = 0; i < 64; ++i) { float w = W1[i*64 + t]; a += W0[i]*w; bg += b0[i]*w; }
    w01[t] = a; g[t] = bg;
  }
  __syncthreads();
  for (int off = 1; off < 256; off <<= 1) {
    int v = (t >= off) ? sums[t - off] : 0;
    __syncthreads();
    sums[t] += v;
    __syncthreads();
  }
  int run = sums[t] - s;
  for (int i = lo; i < hi; ++i) {
    int c = ptr[i];
    ptr[i] = run; cur[i] = run;
    run += c;
  }
  if (t == 255) ptr[N] = run;
  if (t < 64) {
    float w012 = 0.f, P = 0.f, Q = 0.f;
    for (int i = 0; i < 64; ++i) { float w = W2a[i*64 + t]; w012 += w01[i]*w; P += g[i]*w; Q += b1[i]*w; }
    float4 sv; sv.x = w012; sv.y = P; sv.z = Q; sv.w = b2a[t];
    SV4[t] = sv;
    float c0 = br1[t];
    for (int o = 0; o < 16; ++o) {
      float srow = 0.f;
      #pragma unroll
      for (int k = 0; k < 8; ++k) srow += Wr1[(k*16 + o)*64 + t];
      c0 = fmaf(2.f * b2b[o], srow, c0);
    }
    C0[t] = c0;
  }
}

// ---------- CSR fill: csr[cur[dst]++] = src ----------
__global__ void fill_k(const int* __restrict__ ei, int* __restrict__ cur,
                       int* __restrict__ csr, int E) {
  int e = blockIdx.x * blockDim.x + threadIdx.x;
  if (e >= E) return;
  int s = ei[e], d = ei[E + e];
  int pos = atomicAdd(&cur[d], 1);
  csr[pos] = s;
}

#define RED16(v) { v += __shfl_down(v, 8, 16); v += __shfl_down(v, 4, 16); \
                   v += __shfl_down(v, 2, 16); v += __shfl_down(v, 1, 16); }
#define NANFIX4(u) { u.x = (u.x!=u.x)?0.f:u.x; u.y = (u.y!=u.y)?0.f:u.y; \
                     u.z = (u.z!=u.z)?0.f:u.z; u.w = (u.w!=u.w)?0.f:u.w; }

// ---------- vectorized agg: 16 lanes per node, float4 row gathers ----------
template<int MODE>
__global__ __launch_bounds__(256) void aggv_k(
    const int* __restrict__ ptr, const int* __restrict__ csr,
    const float* __restrict__ Fin, const float* __restrict__ Din,
    float* __restrict__ Fout, float* __restrict__ Dout, int N) {
  int g = blockIdx.x * 16 + (threadIdx.x >> 4);
  int t = threadIdx.x & 15;
  if (g >= N) return;
  int lo = ptr[g], hi = ptr[g + 1];
  float a0=0.f,a1=0.f,a2=0.f,a3=0.f,a4=0.f,a5=0.f,a6=0.f,a7=0.f,dd=0.f;
  for (int j = lo + t; j < hi; j += 16) {
    int s = csr[j];
    const float* r = Fin + (size_t)s * 8;
    float4 u0 = *(const float4*)r;
    float4 u1 = *(const float4*)(r + 4);
    if (MODE == 0) { NANFIX4(u0); NANFIX4(u1); }
    a0 += u0.x; a1 += u0.y; a2 += u0.z; a3 += u0.w;
    a4 += u1.x; a5 += u1.y; a6 += u1.z; a7 += u1.w;
    if (MODE == 1) dd += Din[s];
  }
  RED16(a0); RED16(a1); RED16(a2); RED16(a3);
  RED16(a4); RED16(a5); RED16(a6); RED16(a7);
  if (MODE == 1) RED16(dd);
  if (t == 0) {
    const float* r = Fin + (size_t)g * 8;
    float4 s0 = *(const float4*)r;
    float4 s1 = *(const float4*)(r + 4);
    if (MODE == 0) { NANFIX4(s0); NANFIX4(s1); }
    float4 o0 = { a0 + s0.x, a1 + s0.y, a2 + s0.z, a3 + s0.w };
    float4 o1 = { a4 + s1.x, a5 + s1.y, a6 + s1.z, a7 + s1.w };
    *(float4*)(Fout + (size_t)g * 8)     = o0;
    *(float4*)(Fout + (size_t)g * 8 + 4) = o1;
    if (MODE == 0) Dout[g] = 1.f + (float)(hi - lo);
    if (MODE == 1) Dout[g] = Din[g] + dd;
  }
}

// ---------- dense phase: lane = node, zero LDS, all state in registers ----------
// z[h] = C0[h] + sum_k sum_j v[k][j] * M[k][j][h]
// v[k][j] = max(2E_j, E_j + |s_k*w012_j|, 0),  E_j = d2*P_j + d1*Q_j + b2a_j
__global__ __launch_bounds__(64) void dense_k(
    const float* __restrict__ B3, const float* __restrict__ D1, const float* __restrict__ D2,
    const float4* __restrict__ SV4, const float* __restrict__ C0,
    const float* __restrict__ M,
    const float* __restrict__ Wr2, const float* __restrict__ br2,
    const float* __restrict__ x, const float* __restrict__ Wx,
    const float* __restrict__ bx,
    float* __restrict__ out, int N) {
  int n = blockIdx.x * 64 + threadIdx.x;
  bool act = (n < N);
  int nc = act ? n : 0;
  float d1 = D1[nc], d2 = D2[nc];
  float4 s0 = *(const float4*)(B3 + (size_t)nc * 8);
  float4 s1 = *(const float4*)(B3 + (size_t)nc * 8 + 4);
  float s[8] = { s0.x, s0.y, s0.z, s0.w, s1.x, s1.y, s1.z, s1.w };

  // ---- main contraction: z[64] in regs (as 32 x v2f) ----
  v2f z[32];
  const v2f* c0p = (const v2f*)C0;
  #pragma unroll
  for (int h2 = 0; h2 < 32; ++h2) z[h2] = c0p[h2];

  #pragma unroll
  for (int k = 0; k < 8; ++k) {
    float sk = s[k];
    const v2f* Mk = (const v2f*)(M + (size_t)k * 64 * 64);
    #pragma unroll 2
    for (int j = 0; j < 64; ++j) {
      float4 sv = SV4[j];
      float E = fmaf(d2, sv.y, fmaf(d1, sv.z, sv.w));
      float t = sk * sv.x;
      float v = fmaxf(fmaxf(E + E, E + fabsf(t)), 0.f);
      v2f vv; vv.x = v; vv.y = v;
      const v2f* mrow = Mk + j * 32;
      #pragma unroll
      for (int h2 = 0; h2 < 32; ++h2) z[h2] += vv * mrow[h2];
    }
  }

  // ---- rho2: out16 = relu(z) @ Wr2 + br2 ----
  v2f o2[8];
  const v2f* br2p = (const v2f*)br2;
  #pragma unroll
  for (int q = 0; q < 8; ++q) o2[q] = br2p[q];
  #pragma unroll
  for (int h = 0; h < 64; ++h) {
    float zh = (h & 1) ? z[h >> 1].y : z[h >> 1].x;
    zh = fmaxf(zh, 0.f);
    v2f vv; vv.x = zh; vv.y = zh;
    const v2f* wrow = (const v2f*)(Wr2 + h * 16);
    #pragma unroll
    for (int q = 0; q < 8; ++q) o2[q] += vv * wrow[q];
  }
  if (act) {
    float4* op = (float4*)(out + (size_t)n * 128 + 112);
    #pragma unroll
    for (int q4 = 0; q4 < 4; ++q4) {
      float4 st; st.x = o2[2*q4].x; st.y = o2[2*q4].y; st.z = o2[2*q4+1].x; st.w = o2[2*q4+1].y;
      op[q4] = st;
    }
  }

  // ---- expand_x: out[n][0:112] = x[n] @ Wx + bx, two halves of 56 ----
  const float4* xr4 = (const float4*)(x + (size_t)nc * 64);
  for (int half = 0; half < 2; ++half) {
    v2f acc[28];
    const v2f* bxp = (const v2f*)(bx + half * 56);
    #pragma unroll
    for (int q = 0; q < 28; ++q) acc[q] = bxp[q];
    for (int i4 = 0; i4 < 16; ++i4) {
      float4 xv = xr4[i4];
      #pragma unroll
      for (int c = 0; c < 4; ++c) {
        float xs = (c == 0) ? xv.x : (c == 1) ? xv.y : (c == 2) ? xv.z : xv.w;
        v2f vv; vv.x = xs; vv.y = xs;
        const v2f* wrow = (const v2f*)(Wx + (i4 * 4 + c) * 112 + half * 56);
        #pragma unroll
        for (int q = 0; q < 28; ++q) acc[q] += vv * wrow[q];
      }
    }
    if (act) {
      float4* op = (float4*)(out + (size_t)n * 128 + half * 56);
      #pragma unroll
      for (int q4 = 0; q4 < 14; ++q4) {
        float4 st; st.x = acc[2*q4].x; st.y = acc[2*q4].y; st.z = acc[2*q4+1].x; st.w = acc[2*q4+1].y;
        op[q4] = st;
      }
    }
  }
}

extern "C" void kernel_launch(void* const* d_in, const int* in_sizes, int n_in,
                              void* d_out, int out_size, void* d_ws, size_t ws_size,
                              hipStream_t stream) {
  const float* eig = (const float*)d_in[0];
  const float* x   = (const float*)d_in[1];
  const int*   ei  = (const int*)d_in[2];
  const float* W0  = (const float*)d_in[4];
  const float* b0  = (const float*)d_in[5];
  const float* W1  = (const float*)d_in[6];
  const float* b1  = (const float*)d_in[7];
  const float* W2a = (const float*)d_in[8];
  const float* b2a = (const float*)d_in[9];
  const float* W2b = (const float*)d_in[10];
  const float* b2b = (const float*)d_in[11];
  const float* Wr1 = (const float*)d_in[12];
  const float* br1 = (const float*)d_in[13];
  const float* Wr2 = (const float*)d_in[14];
  const float* br2 = (const float*)d_in[15];
  const float* Wx  = (const float*)d_in[16];
  const float* bx  = (const float*)d_in[17];
  float* out = (float*)d_out;

  int N = in_sizes[0] / 8;
  int E = in_sizes[2] / 2;

  int* ptr = (int*)d_ws;                 // N+1
  int* cur = ptr + (N + 1);              // N
  int* csr = cur + N;                    // E
  uintptr_t p = (uintptr_t)(csr + E);
  p = (p + 255) & ~(uintptr_t)255;       // 16B-align for float4 rows
  float* B1  = (float*)p;                // N*8
  float* B2  = B1 + (size_t)N * 8;       // N*8
  float* B3  = B2 + (size_t)N * 8;       // N*8
  float* D1  = B3 + (size_t)N * 8;       // N
  float* D2  = D1 + N;                   // N
  float* SV4 = D2 + N;                   // 256 (64 float4)
  float* C0  = SV4 + 256;                // 64
  float* M   = C0 + 64;                  // 32768

  int eblocks = (E + 255) / 256;
  int nblocks16 = (N + 15) / 16;

  zero_k<<<(N + 256) / 256, 256, 0, stream>>>(ptr, N + 1);
  mk_k<<<128, 256, 0, stream>>>(W2b, Wr1, M);
  hist_k<<<eblocks, 256, 0, stream>>>(ei, ptr, E);
  scan_k<<<1, 256, 0, stream>>>(ptr, cur, N, W0, b0, W1, b1, W2a,
                                b2a, b2b, br1, Wr1, (float4*)SV4, C0);
  fill_k<<<eblocks, 256, 0, stream>>>(ei, cur, csr, E);

  aggv_k<0><<<nblocks16, 256, 0, stream>>>(ptr, csr, eig, nullptr, B1, D1, N);
  aggv_k<1><<<nblocks16, 256, 0, stream>>>(ptr, csr, B1, D1, B2, D2, N);
  aggv_k<2><<<nblocks16, 256, 0, stream>>>(ptr, csr, B2, nullptr, B3, nullptr, N);

  dense_k<<<(N + 63) / 64, 64, 0, stream>>>(B3, D1, D2, (const float4*)SV4, C0, M,
                                            Wr2, br2, x, Wx, bx, out, N);
}